// Round 15
// baseline (162.443 us; speedup 1.0000x reference)
//
#include <hip/hip_runtime.h>

#define S_LEN 4096
#define DMODEL 768
#define NHEADS 12
#define DKH 64
#define SC2F 0.18033688011112042f  // (1/8) * log2(e)

typedef __attribute__((ext_vector_type(8))) short bf16x8;
typedef __attribute__((ext_vector_type(2))) float f32x2;
typedef __attribute__((ext_vector_type(4))) float f32x4;
typedef __attribute__((ext_vector_type(16))) float f32x16;
typedef __attribute__((ext_vector_type(4))) short s16x4;

#define AS1 __attribute__((address_space(1)))
#define AS3 __attribute__((address_space(3)))

#define QSZ ((size_t)NHEADS * S_LEN * DKH)   // elems per po quarter

__device__ __forceinline__ short f2bf(float f) {
    union { float f; unsigned u; } x; x.f = f;
    unsigned r = x.u + 0x7fffu + ((x.u >> 16) & 1u);
    return (short)(r >> 16);
}

__device__ __forceinline__ float bf2f(short s) {
    union { unsigned u; float f; } x;
    x.u = ((unsigned)(unsigned short)s) << 16;
    return x.f;
}

__device__ __forceinline__ void gload_lds16(const void* g, void* l) {
    __builtin_amdgcn_global_load_lds((const AS1 void*)g, (AS3 void*)l, 16, 0, 0);
}

// ---- prep, one launch: z=0..2 q/k/v cvt; z=3..6 W cvt; z=7..10 mask pack ----
__global__ void cvt_all(const float* __restrict__ q, const float* __restrict__ k,
                        const float* __restrict__ v, const float* __restrict__ Wq,
                        const float* __restrict__ Wk, const float* __restrict__ Wv,
                        const float* __restrict__ Wo,
                        short* __restrict__ qb, short* __restrict__ kb,
                        short* __restrict__ vb, short* __restrict__ Wb,
                        const int* __restrict__ mask, unsigned long long* __restrict__ mpT) {
    const int z = blockIdx.z;
    if (z >= 7) {
        // mask int32 [S][S] -> transposed bitmask [S/64 kblk][S row]
        int lane = threadIdx.x & 63;
        int wid = (blockIdx.x * blockDim.x + threadIdx.x) >> 6;
        int nw = (gridDim.x * blockDim.x) >> 6;      // 2048
        int base = (z - 7) * 65536;
        for (int w = base + wid; w < base + 65536; w += nw) {
            int m = mask[(size_t)w * 64 + lane];
            unsigned long long b = __ballot(m != 0);
            if (lane == 0) mpT[(size_t)(w & 63) * S_LEN + (w >> 6)] = b;
        }
        return;
    }
    const float* s;
    short* d;
    int n8;
    if (z < 3) {
        s = z == 0 ? q : z == 1 ? k : v;
        d = z == 0 ? qb : z == 1 ? kb : vb;
        n8 = S_LEN * DMODEL / 8;
    } else {
        s = z == 3 ? Wq : z == 4 ? Wk : z == 5 ? Wv : Wo;
        d = Wb + (size_t)(z - 3) * (DMODEL * DMODEL);
        n8 = DMODEL * DMODEL / 8;
    }
    int stride = gridDim.x * blockDim.x;
    for (int i = blockIdx.x * blockDim.x + threadIdx.x; i < n8; i += stride) {
        float4 x = ((const float4*)s)[2 * i];
        float4 y = ((const float4*)s)[2 * i + 1];
        bf16x8 o;
        o[0] = f2bf(x.x); o[1] = f2bf(x.y); o[2] = f2bf(x.z); o[3] = f2bf(x.w);
        o[4] = f2bf(y.x); o[5] = f2bf(y.y); o[6] = f2bf(y.z); o[7] = f2bf(y.w);
        ((bf16x8*)d)[i] = o;
    }
}

// ------- QKV projection GEMMs, M-tile 64 x N-tile 256 (grid 64x3x3) ----------
// Per-wave 64x64 output (acc[4][4]) -> 16 ds_read_b128 per 32 MFMA (1:2).
// Staging/swizzle/fragment/epilogue formulas verbatim from the proven r12
// kernel; only tile constants changed. Output bit-identical (same K order).
__global__ __launch_bounds__(256) void qkv_gemm(
    const short* __restrict__ qA, const short* __restrict__ kA, const short* __restrict__ vA,
    const short* __restrict__ Wqb, const short* __restrict__ Wkb, const short* __restrict__ Wvb,
    const float* __restrict__ bq, const float* __restrict__ bk, const float* __restrict__ bv,
    short* __restrict__ Qh, short* __restrict__ Kh, short* __restrict__ Vt)
{
    const int z = blockIdx.z;
    const short* A = z == 0 ? qA : z == 1 ? kA : vA;
    const short* B = z == 0 ? Wqb : z == 1 ? Wkb : Wvb;
    const float* bias = z == 0 ? bq : z == 1 ? bk : bv;

    __shared__ __align__(16) short As[64 * 64];
    __shared__ __align__(16) short Bs[256 * 64];
    const int tid = threadIdx.x;
    const int wv = tid >> 6, l = tid & 63;
    const int g = l >> 4, hl = l & 15;
    const int m0 = blockIdx.x * 64, n0 = blockIdx.y * 256;
    const int Kd = DMODEL;

    f32x4 acc[4][4] = {};

    for (int kt = 0; kt < Kd; kt += 64) {
        __syncthreads();
        #pragma unroll
        for (int i = 0; i < 2; ++i) {
            int row = i * 32 + wv * 8 + (l >> 3);
            int csrc = (l & 7) ^ (row & 7);
            gload_lds16(A + (size_t)(m0 + row) * Kd + kt + csrc * 8, As + (i * 32 + wv * 8) * 64);
        }
        #pragma unroll
        for (int i = 0; i < 8; ++i) {
            int row = i * 32 + wv * 8 + (l >> 3);
            int csrc = (l & 7) ^ (row & 7);
            gload_lds16(B + (size_t)(n0 + row) * Kd + kt + csrc * 8, Bs + (i * 32 + wv * 8) * 64);
        }
        __syncthreads();
        #pragma unroll
        for (int s = 0; s < 2; ++s) {
            bf16x8 af[4], bf[4];
            #pragma unroll
            for (int m = 0; m < 4; ++m) {
                int row = m * 16 + hl;
                int ch = (s * 4 + g) ^ (row & 7);
                af[m] = *(const bf16x8*)(As + row * 64 + ch * 8);
            }
            #pragma unroll
            for (int n = 0; n < 4; ++n) {
                int row = wv * 64 + n * 16 + hl;
                int ch = (s * 4 + g) ^ (row & 7);
                bf[n] = *(const bf16x8*)(Bs + row * 64 + ch * 8);
            }
            #pragma unroll
            for (int m = 0; m < 4; ++m)
                #pragma unroll
                for (int n = 0; n < 4; ++n)
                    acc[m][n] = __builtin_amdgcn_mfma_f32_16x16x32_bf16(af[m], bf[n], acc[m][n], 0, 0, 0);
        }
    }

    const float scale = (z == 0) ? SC2F : 1.0f;
    #pragma unroll
    for (int m = 0; m < 4; ++m) {
        #pragma unroll
        for (int n = 0; n < 4; ++n) {
            int gsb = m0 + m * 16 + g * 4;
            int go = n0 + wv * 64 + n * 16 + hl;
            float bvv = bias[go];
            int hh = go >> 6, d = go & 63;
            if (z == 2) {
                s16x4 p;
                #pragma unroll
                for (int r = 0; r < 4; ++r) p[r] = f2bf(acc[m][n][r] + bvv);
                // swap bits 2,3 of the kv index (bits 0,1 are within the quad)
                int gsb2 = (gsb & ~12) | ((gsb & 4) << 1) | ((gsb & 8) >> 1);
                *(s16x4*)(Vt + (size_t)hh * DKH * S_LEN + (size_t)d * S_LEN + gsb2) = p;
            } else {
                short* O = z ? Kh : Qh;
                #pragma unroll
                for (int r = 0; r < 4; ++r)
                    O[(size_t)hh * S_LEN * DKH + (size_t)(gsb + r) * DKH + d] = f2bf((acc[m][n][r] + bvv) * scale);
            }
        }
    }
}

// --- output projection, M-tile 64, fused 4-way split-K merge (fp32 + bias) ---
__global__ __launch_bounds__(256) void gemm_out(
    const short* __restrict__ poA, const short* __restrict__ po3,
    const float* __restrict__ pd, const short* __restrict__ B,
    const float* __restrict__ bias, float* __restrict__ O)
{
    __shared__ __align__(16) short As[64 * 64];
    __shared__ __align__(16) short Bs[128 * 64];
    const int tid = threadIdx.x;
    const int wv = tid >> 6, l = tid & 63;
    const int wc = wv;
    const int g = l >> 4, hl = l & 15;
    const int m0 = blockIdx.x * 64, n0 = blockIdx.y * 128;
    const int Kd = DMODEL;

    f32x4 acc[4][2] = {};

    for (int kt = 0; kt < Kd; kt += 64) {
        __syncthreads();
        const int h = kt >> 6;   // A columns kt..kt+63 = head h, d 0..63
        #pragma unroll
        for (int i = 0; i < 2; ++i) {
            int row = i * 32 + wv * 8 + (l >> 3);
            int csrc = (l & 7) ^ (row & 7);
            size_t rb = (size_t)h * S_LEN + m0 + row;
            size_t base = rb * DKH + csrc * 8;
            bf16x8 a0 = *(const bf16x8*)(poA + base);
            bf16x8 a1 = *(const bf16x8*)(poA + QSZ + base);
            bf16x8 a2 = *(const bf16x8*)(poA + 2 * QSZ + base);
            bf16x8 a3 = *(const bf16x8*)(po3 + base);
            float inv = 1.0f / (pd[rb] + pd[NHEADS * S_LEN + rb]
                              + pd[2 * NHEADS * S_LEN + rb] + pd[3 * NHEADS * S_LEN + rb]);
            bf16x8 o;
            #pragma unroll
            for (int e = 0; e < 8; ++e)
                o[e] = f2bf((bf2f(a0[e]) + bf2f(a1[e]) + bf2f(a2[e]) + bf2f(a3[e])) * inv);
            *(bf16x8*)(As + (i * 32 + wv * 8) * 64 + l * 8) = o;
        }
        #pragma unroll
        for (int i = 0; i < 4; ++i) {
            int row = i * 32 + wv * 8 + (l >> 3);
            int csrc = (l & 7) ^ (row & 7);
            gload_lds16(B + (size_t)(n0 + row) * Kd + kt + csrc * 8, Bs + (i * 32 + wv * 8) * 64);
        }
        __syncthreads();
        #pragma unroll
        for (int s = 0; s < 2; ++s) {
            bf16x8 af[4], bf[2];
            #pragma unroll
            for (int m = 0; m < 4; ++m) {
                int row = m * 16 + hl;
                int ch = (s * 4 + g) ^ (row & 7);
                af[m] = *(const bf16x8*)(As + row * 64 + ch * 8);
            }
            #pragma unroll
            for (int n = 0; n < 2; ++n) {
                int row = wc * 32 + n * 16 + hl;
                int ch = (s * 4 + g) ^ (row & 7);
                bf[n] = *(const bf16x8*)(Bs + row * 64 + ch * 8);
            }
            #pragma unroll
            for (int m = 0; m < 4; ++m)
                #pragma unroll
                for (int n = 0; n < 2; ++n)
                    acc[m][n] = __builtin_amdgcn_mfma_f32_16x16x32_bf16(af[m], bf[n], acc[m][n], 0, 0, 0);
        }
    }

    #pragma unroll
    for (int m = 0; m < 4; ++m) {
        #pragma unroll
        for (int n = 0; n < 2; ++n) {
            int gsb = m0 + m * 16 + g * 4;
            int go = n0 + wc * 32 + n * 16 + hl;
            float bvv = bias[go];
            #pragma unroll
            for (int r = 0; r < 4; ++r)
                O[(size_t)(gsb + r) * DMODEL + go] = acc[m][n][r] + bvv;
        }
    }
}

// ------------- flash attention: 4-way split-K, reduced-VALU softmax ----------
__global__ __launch_bounds__(512) void flash_attn6(
    const short* __restrict__ Qh, const short* __restrict__ Kh,
    const short* __restrict__ Vt, const unsigned long long* __restrict__ mpT,
    short* __restrict__ poA, short* __restrict__ po3, float* __restrict__ pd)
{
    __shared__ __align__(16) char pool[35328];

    const int tid = threadIdx.x;
    const int wv = tid >> 6, l = tid & 63;
    const int wq = wv >> 1, sp = wv & 1;
    const int hi = l >> 5, q = l & 31;

    // XCD-chunked remap: 1536 blocks -> 192 consecutive work items per XCD.
    int fid = blockIdx.x;
    int g = (fid & 7) * 192 + (fid >> 3);
    const int h = g >> 7;
    const int sub = g & 127;
    const int quart = sub >> 5;
    const int q0 = (sub & 31) * 128;

    const short* Khb = Kh + (size_t)h * S_LEN * DKH;
    const short* Vtb = Vt + (size_t)h * DKH * S_LEN;
    const int qrow = q0 + wq * 32 + q;

    bf16x8 aq[4];
    #pragma unroll
    for (int s = 0; s < 4; ++s)
        aq[s] = *(const bf16x8*)(Qh + (size_t)h * S_LEN * DKH + (size_t)qrow * DKH + s * 16 + hi * 8);

    f32x16 acc[2] = {};
    f32x2 d01 = {0.f, 0.f}, d23 = {0.f, 0.f};

    short* Kl = (short*)(pool + sp * 8192);           // [0, 16384)
    short* Vl = (short*)(pool + 16384 + sp * 8192);   // [16384, 32768)

    for (int i = 0; i < 8; ++i) {
        const int kt = quart * 16 + i * 2 + sp;
        const int kv0 = kt * 64;
        __syncthreads();
        #pragma unroll
        for (int j = 0; j < 2; ++j) {
            int rp = (wq * 2 + j) * 4 + (l >> 4);
            int x = (l & 15) ^ (rp & 15);
            int row = rp * 2 + (x >> 3);
            int c = x & 7;
            gload_lds16(Khb + (size_t)(kv0 + row) * DKH + c * 8, Kl + (wq * 2 + j) * 512);
            gload_lds16(Vtb + (size_t)row * S_LEN + kv0 + c * 8, Vl + (wq * 2 + j) * 512);
        }
        unsigned long long w = mpT[(size_t)kt * S_LEN + qrow];
        __syncthreads();

        unsigned long long w2 = w >> (hi * 4);
        unsigned mlo = (unsigned)w2, mhi2 = (unsigned)(w2 >> 32);

        #pragma unroll
        for (int t = 0; t < 2; ++t) {
            const unsigned msk = t ? mhi2 : mlo;
            f32x16 st = {};
            __builtin_amdgcn_s_setprio(1);
            #pragma unroll
            for (int s = 0; s < 4; ++s) {
                int rowb = t * 32 + q;
                int rp = rowb >> 1;
                int ch = (((rowb & 1) << 3) + (s * 2 + hi)) ^ (rp & 15);
                bf16x8 kf = *(const bf16x8*)(Kl + rp * 128 + ch * 8);
                st = __builtin_amdgcn_mfma_f32_32x32x16_bf16(kf, aq[s], st, 0, 0, 0);
            }
            __builtin_amdgcn_s_setprio(0);
            // P = exp2(score) AND sext(maskbit): masked -> exact 0.0
            float pf[16];
            #pragma unroll
            for (int r = 0; r < 16; ++r) {
                const int cbit = (r & 3) + 8 * (r >> 2);
                unsigned mb;
                asm("v_bfe_i32 %0, %1, %2, 1" : "=v"(mb) : "v"(msk), "i"(cbit));
                union { float f; unsigned u; } e;
                e.f = __builtin_amdgcn_exp2f(st[r]);
                e.u &= mb;
                pf[r] = e.f;
            }
            #pragma unroll
            for (int rr = 0; rr < 16; rr += 4) {
                d01 += (f32x2){pf[rr], pf[rr + 1]};
                d23 += (f32x2){pf[rr + 2], pf[rr + 3]};
            }
            __builtin_amdgcn_s_setprio(1);
            #pragma unroll
            for (int kk = 0; kk < 2; ++kk) {
                const float* pp = pf + kk * 8;
                union { unsigned u[4]; bf16x8 v; } pa;
                asm("v_cvt_pk_bf16_f32 %0, %1, %2" : "=v"(pa.u[0]) : "v"(pp[0]), "v"(pp[1]));
                asm("v_cvt_pk_bf16_f32 %0, %1, %2" : "=v"(pa.u[1]) : "v"(pp[2]), "v"(pp[3]));
                asm("v_cvt_pk_bf16_f32 %0, %1, %2" : "=v"(pa.u[2]) : "v"(pp[4]), "v"(pp[5]));
                asm("v_cvt_pk_bf16_f32 %0, %1, %2" : "=v"(pa.u[3]) : "v"(pp[6]), "v"(pp[7]));
                const int ks = t * 2 + kk;
                #pragma unroll
                for (int dt = 0; dt < 2; ++dt) {
                    int rowb = dt * 32 + q;
                    int rp = rowb >> 1;
                    int ch = (((rowb & 1) << 3) + (ks * 2 + hi)) ^ (rp & 15);
                    bf16x8 vf = *(const bf16x8*)(Vl + rp * 128 + ch * 8);
                    acc[dt] = __builtin_amdgcn_mfma_f32_32x32x16_bf16(pa.v, vf, acc[dt], 0, 0, 0);
                }
            }
            __builtin_amdgcn_s_setprio(0);
        }
    }

    const float dsum = d01[0] + d01[1] + d23[0] + d23[1];

    // merge sp halves through LDS (pure adds); write undivided partials
    __syncthreads();
    float* accb = (float*)pool;                    // [4 wq x 2 dt][16 r][64 l] = 32 KB
    float* ddb  = (float*)(pool + 32768);          // [8 wv][64 l] = 2 KB
    ddb[wv * 64 + l] = dsum;
    if (sp == 1) {
        #pragma unroll
        for (int dt = 0; dt < 2; ++dt)
            #pragma unroll
            for (int r = 0; r < 16; ++r)
                accb[(((wq * 2 + dt) * 16 + r) << 6) + l] = acc[dt][r];
    }
    __syncthreads();
    if (sp == 0) {
        short* po = (quart < 3) ? (short*)(poA + (size_t)quart * QSZ) : po3;
        float dq = ddb[(wq * 2) * 64 + q] + ddb[(wq * 2) * 64 + 32 + q]
                 + ddb[(wq * 2 + 1) * 64 + q] + ddb[(wq * 2 + 1) * 64 + 32 + q];
        if (hi == 0) pd[(size_t)quart * (NHEADS * S_LEN) + (size_t)h * S_LEN + q0 + wq * 32 + q] = dq;
        #pragma unroll
        for (int dt = 0; dt < 2; ++dt) {
            #pragma unroll
            for (int r = 0; r < 16; ++r) {
                float o = acc[dt][r] + accb[(((wq * 2 + dt) * 16 + r) << 6) + l];
                int qo = (r & 3) + 8 * (r >> 2) + 4 * hi;
                po[((size_t)h * S_LEN + q0 + wq * 32 + qo) * DKH + dt * 32 + q] = f2bf(o);
            }
        }
    }
}

extern "C" void kernel_launch(void* const* d_in, const int* in_sizes, int n_in,
                              void* d_out, int out_size, void* d_ws, size_t ws_size,
                              hipStream_t stream) {
    (void)in_sizes; (void)n_in; (void)out_size; (void)ws_size;
    const float* q  = (const float*)d_in[0];
    const float* k  = (const float*)d_in[1];
    const float* v  = (const float*)d_in[2];
    const float* Wq = (const float*)d_in[3];
    const float* bq = (const float*)d_in[4];
    const float* Wk = (const float*)d_in[5];
    const float* bk = (const float*)d_in[6];
    const float* Wv = (const float*)d_in[7];
    const float* bv = (const float*)d_in[8];
    const float* Wo = (const float*)d_in[9];
    const float* bo = (const float*)d_in[10];
    const int* mask = (const int*)d_in[11];

    char* ws = (char*)d_ws;
    short* qb  = (short*)(ws + 0);
    short* kb  = (short*)(ws + 6291456);
    short* vb  = (short*)(ws + 12582912);
    short* Wqb = (short*)(ws + 18874368);   // Wq/Wk/Wv/Wo contiguous, 1179648 B each
    short* Wkb = (short*)(ws + 20054016);
    short* Wvb = (short*)(ws + 21233664);
    short* Wob = (short*)(ws + 22413312);
    short* Qh  = (short*)(ws + 23592960);
    short* Kh  = (short*)(ws + 29884416);
    short* Vt  = (short*)(ws + 36175872);
    unsigned long long* mpT = (unsigned long long*)(ws + 42467328);
    // flash partials overlay DEAD regions (after qkv_gemm, W q/k/v + inputs are dead):
    short* poA = (short*)(ws + 0);          // quarters 0-2: 3 x 6291456 B = [0, 18874368)
    float* pd  = (float*)(ws + 18874368);   // 786432 B (over dead Wqb/Wkb space)
    short* po3 = (short*)(ws + 44564480);   // quarter 3: 6291456 B (old ctx region)
    // Wob at 22413312 stays live for gemm_out. Total ws use: 50855936 bytes.

    cvt_all<<<dim3(512, 1, 11), 256, 0, stream>>>(q, k, v, Wq, Wk, Wv, Wo, qb, kb, vb, Wqb, mask, mpT);

    qkv_gemm<<<dim3(S_LEN / 64, DMODEL / 256, 3), 256, 0, stream>>>(
        qb, kb, vb, Wqb, Wkb, Wvb, bq, bk, bv, Qh, Kh, Vt);

    flash_attn6<<<1536, 512, 0, stream>>>(Qh, Kh, Vt, mpT, poA, po3, pd);

    gemm_out<<<dim3(S_LEN / 64, DMODEL / 128), 256, 0, stream>>>(poA, po3, pd, Wob, bo, (float*)d_out);
}

// Round 16
// 149.919 us; speedup vs baseline: 1.0835x; 1.0835x over previous
//
#include <hip/hip_runtime.h>

#define S_LEN 4096
#define DMODEL 768
#define NHEADS 12
#define DKH 64
#define SC2F 0.18033688011112042f  // (1/8) * log2(e)

typedef __attribute__((ext_vector_type(8))) short bf16x8;
typedef __attribute__((ext_vector_type(2))) float f32x2;
typedef __attribute__((ext_vector_type(4))) float f32x4;
typedef __attribute__((ext_vector_type(16))) float f32x16;
typedef __attribute__((ext_vector_type(4))) short s16x4;

#define AS1 __attribute__((address_space(1)))
#define AS3 __attribute__((address_space(3)))

#define QSZ ((size_t)NHEADS * S_LEN * DKH)   // elems per po quarter

__device__ __forceinline__ short f2bf(float f) {
    union { float f; unsigned u; } x; x.f = f;
    unsigned r = x.u + 0x7fffu + ((x.u >> 16) & 1u);
    return (short)(r >> 16);
}

__device__ __forceinline__ float bf2f(short s) {
    union { unsigned u; float f; } x;
    x.u = ((unsigned)(unsigned short)s) << 16;
    return x.f;
}

__device__ __forceinline__ void gload_lds16(const void* g, void* l) {
    __builtin_amdgcn_global_load_lds((const AS1 void*)g, (AS3 void*)l, 16, 0, 0);
}

// ---- prep, one launch: z=0..2 q/k/v cvt; z=3..6 W cvt; z=7..10 mask pack ----
__global__ void cvt_all(const float* __restrict__ q, const float* __restrict__ k,
                        const float* __restrict__ v, const float* __restrict__ Wq,
                        const float* __restrict__ Wk, const float* __restrict__ Wv,
                        const float* __restrict__ Wo,
                        short* __restrict__ qb, short* __restrict__ kb,
                        short* __restrict__ vb, short* __restrict__ Wb,
                        const int* __restrict__ mask, unsigned long long* __restrict__ mpT) {
    const int z = blockIdx.z;
    if (z >= 7) {
        // mask int32 [S][S] -> transposed bitmask [S/64 kblk][S row]
        int lane = threadIdx.x & 63;
        int wid = (blockIdx.x * blockDim.x + threadIdx.x) >> 6;
        int nw = (gridDim.x * blockDim.x) >> 6;      // 2048
        int base = (z - 7) * 65536;
        for (int w = base + wid; w < base + 65536; w += nw) {
            int m = mask[(size_t)w * 64 + lane];
            unsigned long long b = __ballot(m != 0);
            if (lane == 0) mpT[(size_t)(w & 63) * S_LEN + (w >> 6)] = b;
        }
        return;
    }
    const float* s;
    short* d;
    int n8;
    if (z < 3) {
        s = z == 0 ? q : z == 1 ? k : v;
        d = z == 0 ? qb : z == 1 ? kb : vb;
        n8 = S_LEN * DMODEL / 8;
    } else {
        s = z == 3 ? Wq : z == 4 ? Wk : z == 5 ? Wv : Wo;
        d = Wb + (size_t)(z - 3) * (DMODEL * DMODEL);
        n8 = DMODEL * DMODEL / 8;
    }
    int stride = gridDim.x * blockDim.x;
    for (int i = blockIdx.x * blockDim.x + threadIdx.x; i < n8; i += stride) {
        float4 x = ((const float4*)s)[2 * i];
        float4 y = ((const float4*)s)[2 * i + 1];
        bf16x8 o;
        o[0] = f2bf(x.x); o[1] = f2bf(x.y); o[2] = f2bf(x.z); o[3] = f2bf(x.w);
        o[4] = f2bf(y.x); o[5] = f2bf(y.y); o[6] = f2bf(y.z); o[7] = f2bf(y.w);
        ((bf16x8*)d)[i] = o;
    }
}

// ---------------- QKV projection GEMMs, M-tile 64 (grid 64x6x3) ----------------
__global__ __launch_bounds__(256) void qkv_gemm(
    const short* __restrict__ qA, const short* __restrict__ kA, const short* __restrict__ vA,
    const short* __restrict__ Wqb, const short* __restrict__ Wkb, const short* __restrict__ Wvb,
    const float* __restrict__ bq, const float* __restrict__ bk, const float* __restrict__ bv,
    short* __restrict__ Qh, short* __restrict__ Kh, short* __restrict__ Vt)
{
    const int z = blockIdx.z;
    const short* A = z == 0 ? qA : z == 1 ? kA : vA;
    const short* B = z == 0 ? Wqb : z == 1 ? Wkb : Wvb;
    const float* bias = z == 0 ? bq : z == 1 ? bk : bv;

    __shared__ __align__(16) short As[64 * 64];
    __shared__ __align__(16) short Bs[128 * 64];
    const int tid = threadIdx.x;
    const int wv = tid >> 6, l = tid & 63;
    const int wc = wv;
    const int g = l >> 4, hl = l & 15;
    const int m0 = blockIdx.x * 64, n0 = blockIdx.y * 128;
    const int Kd = DMODEL;

    f32x4 acc[4][2] = {};

    for (int kt = 0; kt < Kd; kt += 64) {
        __syncthreads();
        #pragma unroll
        for (int i = 0; i < 2; ++i) {
            int row = i * 32 + wv * 8 + (l >> 3);
            int csrc = (l & 7) ^ (row & 7);
            gload_lds16(A + (size_t)(m0 + row) * Kd + kt + csrc * 8, As + (i * 32 + wv * 8) * 64);
        }
        #pragma unroll
        for (int i = 0; i < 4; ++i) {
            int row = i * 32 + wv * 8 + (l >> 3);
            int csrc = (l & 7) ^ (row & 7);
            gload_lds16(B + (size_t)(n0 + row) * Kd + kt + csrc * 8, Bs + (i * 32 + wv * 8) * 64);
        }
        __syncthreads();
        #pragma unroll
        for (int s = 0; s < 2; ++s) {
            bf16x8 af[4], bf[2];
            #pragma unroll
            for (int m = 0; m < 4; ++m) {
                int row = m * 16 + hl;
                int ch = (s * 4 + g) ^ (row & 7);
                af[m] = *(const bf16x8*)(As + row * 64 + ch * 8);
            }
            #pragma unroll
            for (int n = 0; n < 2; ++n) {
                int row = wc * 32 + n * 16 + hl;
                int ch = (s * 4 + g) ^ (row & 7);
                bf[n] = *(const bf16x8*)(Bs + row * 64 + ch * 8);
            }
            #pragma unroll
            for (int m = 0; m < 4; ++m)
                #pragma unroll
                for (int n = 0; n < 2; ++n)
                    acc[m][n] = __builtin_amdgcn_mfma_f32_16x16x32_bf16(af[m], bf[n], acc[m][n], 0, 0, 0);
        }
    }

    const float scale = (z == 0) ? SC2F : 1.0f;
    #pragma unroll
    for (int m = 0; m < 4; ++m) {
        #pragma unroll
        for (int n = 0; n < 2; ++n) {
            int gsb = m0 + m * 16 + g * 4;
            int go = n0 + wc * 32 + n * 16 + hl;
            float bvv = bias[go];
            int hh = go >> 6, d = go & 63;
            if (z == 2) {
                s16x4 p;
                #pragma unroll
                for (int r = 0; r < 4; ++r) p[r] = f2bf(acc[m][n][r] + bvv);
                // swap bits 2,3 of the kv index (bits 0,1 are within the quad)
                int gsb2 = (gsb & ~12) | ((gsb & 4) << 1) | ((gsb & 8) >> 1);
                *(s16x4*)(Vt + (size_t)hh * DKH * S_LEN + (size_t)d * S_LEN + gsb2) = p;
            } else {
                short* O = z ? Kh : Qh;
                #pragma unroll
                for (int r = 0; r < 4; ++r)
                    O[(size_t)hh * S_LEN * DKH + (size_t)(gsb + r) * DKH + d] = f2bf((acc[m][n][r] + bvv) * scale);
            }
        }
    }
}

// --- output projection, M-tile 64, fused 4-way split-K merge (fp32 + bias) ---
__global__ __launch_bounds__(256) void gemm_out(
    const short* __restrict__ poA, const short* __restrict__ po3,
    const float* __restrict__ pd, const short* __restrict__ B,
    const float* __restrict__ bias, float* __restrict__ O)
{
    __shared__ __align__(16) short As[64 * 64];
    __shared__ __align__(16) short Bs[128 * 64];
    const int tid = threadIdx.x;
    const int wv = tid >> 6, l = tid & 63;
    const int wc = wv;
    const int g = l >> 4, hl = l & 15;
    const int m0 = blockIdx.x * 64, n0 = blockIdx.y * 128;
    const int Kd = DMODEL;

    f32x4 acc[4][2] = {};

    for (int kt = 0; kt < Kd; kt += 64) {
        __syncthreads();
        const int h = kt >> 6;   // A columns kt..kt+63 = head h, d 0..63
        #pragma unroll
        for (int i = 0; i < 2; ++i) {
            int row = i * 32 + wv * 8 + (l >> 3);
            int csrc = (l & 7) ^ (row & 7);
            size_t rb = (size_t)h * S_LEN + m0 + row;
            size_t base = rb * DKH + csrc * 8;
            bf16x8 a0 = *(const bf16x8*)(poA + base);
            bf16x8 a1 = *(const bf16x8*)(poA + QSZ + base);
            bf16x8 a2 = *(const bf16x8*)(poA + 2 * QSZ + base);
            bf16x8 a3 = *(const bf16x8*)(po3 + base);
            float inv = 1.0f / (pd[rb] + pd[NHEADS * S_LEN + rb]
                              + pd[2 * NHEADS * S_LEN + rb] + pd[3 * NHEADS * S_LEN + rb]);
            bf16x8 o;
            #pragma unroll
            for (int e = 0; e < 8; ++e)
                o[e] = f2bf((bf2f(a0[e]) + bf2f(a1[e]) + bf2f(a2[e]) + bf2f(a3[e])) * inv);
            *(bf16x8*)(As + (i * 32 + wv * 8) * 64 + l * 8) = o;
        }
        #pragma unroll
        for (int i = 0; i < 4; ++i) {
            int row = i * 32 + wv * 8 + (l >> 3);
            int csrc = (l & 7) ^ (row & 7);
            gload_lds16(B + (size_t)(n0 + row) * Kd + kt + csrc * 8, Bs + (i * 32 + wv * 8) * 64);
        }
        __syncthreads();
        #pragma unroll
        for (int s = 0; s < 2; ++s) {
            bf16x8 af[4], bf[2];
            #pragma unroll
            for (int m = 0; m < 4; ++m) {
                int row = m * 16 + hl;
                int ch = (s * 4 + g) ^ (row & 7);
                af[m] = *(const bf16x8*)(As + row * 64 + ch * 8);
            }
            #pragma unroll
            for (int n = 0; n < 2; ++n) {
                int row = wc * 32 + n * 16 + hl;
                int ch = (s * 4 + g) ^ (row & 7);
                bf[n] = *(const bf16x8*)(Bs + row * 64 + ch * 8);
            }
            #pragma unroll
            for (int m = 0; m < 4; ++m)
                #pragma unroll
                for (int n = 0; n < 2; ++n)
                    acc[m][n] = __builtin_amdgcn_mfma_f32_16x16x32_bf16(af[m], bf[n], acc[m][n], 0, 0, 0);
        }
    }

    #pragma unroll
    for (int m = 0; m < 4; ++m) {
        #pragma unroll
        for (int n = 0; n < 2; ++n) {
            int gsb = m0 + m * 16 + g * 4;
            int go = n0 + wc * 32 + n * 16 + hl;
            float bvv = bias[go];
            #pragma unroll
            for (int r = 0; r < 4; ++r)
                O[(size_t)(gsb + r) * DMODEL + go] = acc[m][n][r] + bvv;
        }
    }
}

// ------------- flash attention: 4-way split-K, reduced-VALU softmax ----------
__global__ __launch_bounds__(512) void flash_attn6(
    const short* __restrict__ Qh, const short* __restrict__ Kh,
    const short* __restrict__ Vt, const unsigned long long* __restrict__ mpT,
    short* __restrict__ poA, short* __restrict__ po3, float* __restrict__ pd)
{
    __shared__ __align__(16) char pool[35328];

    const int tid = threadIdx.x;
    const int wv = tid >> 6, l = tid & 63;
    const int wq = wv >> 1, sp = wv & 1;
    const int hi = l >> 5, q = l & 31;

    // XCD-chunked remap: 1536 blocks -> 192 consecutive work items per XCD.
    int fid = blockIdx.x;
    int g = (fid & 7) * 192 + (fid >> 3);
    const int h = g >> 7;
    const int sub = g & 127;
    const int quart = sub >> 5;
    const int q0 = (sub & 31) * 128;

    const short* Khb = Kh + (size_t)h * S_LEN * DKH;
    const short* Vtb = Vt + (size_t)h * DKH * S_LEN;
    const int qrow = q0 + wq * 32 + q;

    bf16x8 aq[4];
    #pragma unroll
    for (int s = 0; s < 4; ++s)
        aq[s] = *(const bf16x8*)(Qh + (size_t)h * S_LEN * DKH + (size_t)qrow * DKH + s * 16 + hi * 8);

    f32x16 acc[2] = {};
    f32x2 d01 = {0.f, 0.f}, d23 = {0.f, 0.f};

    short* Kl = (short*)(pool + sp * 8192);           // [0, 16384)
    short* Vl = (short*)(pool + 16384 + sp * 8192);   // [16384, 32768)

    for (int i = 0; i < 8; ++i) {
        const int kt = quart * 16 + i * 2 + sp;
        const int kv0 = kt * 64;
        __syncthreads();
        #pragma unroll
        for (int j = 0; j < 2; ++j) {
            int rp = (wq * 2 + j) * 4 + (l >> 4);
            int x = (l & 15) ^ (rp & 15);
            int row = rp * 2 + (x >> 3);
            int c = x & 7;
            gload_lds16(Khb + (size_t)(kv0 + row) * DKH + c * 8, Kl + (wq * 2 + j) * 512);
            gload_lds16(Vtb + (size_t)row * S_LEN + kv0 + c * 8, Vl + (wq * 2 + j) * 512);
        }
        unsigned long long w = mpT[(size_t)kt * S_LEN + qrow];
        __syncthreads();

        unsigned long long w2 = w >> (hi * 4);
        unsigned mlo = (unsigned)w2, mhi2 = (unsigned)(w2 >> 32);

        #pragma unroll
        for (int t = 0; t < 2; ++t) {
            const unsigned msk = t ? mhi2 : mlo;
            f32x16 st = {};
            __builtin_amdgcn_s_setprio(1);
            #pragma unroll
            for (int s = 0; s < 4; ++s) {
                int rowb = t * 32 + q;
                int rp = rowb >> 1;
                int ch = (((rowb & 1) << 3) + (s * 2 + hi)) ^ (rp & 15);
                bf16x8 kf = *(const bf16x8*)(Kl + rp * 128 + ch * 8);
                st = __builtin_amdgcn_mfma_f32_32x32x16_bf16(kf, aq[s], st, 0, 0, 0);
            }
            __builtin_amdgcn_s_setprio(0);
            // P = exp2(score) AND sext(maskbit): masked -> exact 0.0
            float pf[16];
            #pragma unroll
            for (int r = 0; r < 16; ++r) {
                const int cbit = (r & 3) + 8 * (r >> 2);
                unsigned mb;
                asm("v_bfe_i32 %0, %1, %2, 1" : "=v"(mb) : "v"(msk), "i"(cbit));
                union { float f; unsigned u; } e;
                e.f = __builtin_amdgcn_exp2f(st[r]);
                e.u &= mb;
                pf[r] = e.f;
            }
            #pragma unroll
            for (int rr = 0; rr < 16; rr += 4) {
                d01 += (f32x2){pf[rr], pf[rr + 1]};
                d23 += (f32x2){pf[rr + 2], pf[rr + 3]};
            }
            __builtin_amdgcn_s_setprio(1);
            #pragma unroll
            for (int kk = 0; kk < 2; ++kk) {
                const float* pp = pf + kk * 8;
                union { unsigned u[4]; bf16x8 v; } pa;
                asm("v_cvt_pk_bf16_f32 %0, %1, %2" : "=v"(pa.u[0]) : "v"(pp[0]), "v"(pp[1]));
                asm("v_cvt_pk_bf16_f32 %0, %1, %2" : "=v"(pa.u[1]) : "v"(pp[2]), "v"(pp[3]));
                asm("v_cvt_pk_bf16_f32 %0, %1, %2" : "=v"(pa.u[2]) : "v"(pp[4]), "v"(pp[5]));
                asm("v_cvt_pk_bf16_f32 %0, %1, %2" : "=v"(pa.u[3]) : "v"(pp[6]), "v"(pp[7]));
                const int ks = t * 2 + kk;
                #pragma unroll
                for (int dt = 0; dt < 2; ++dt) {
                    int rowb = dt * 32 + q;
                    int rp = rowb >> 1;
                    int ch = (((rowb & 1) << 3) + (ks * 2 + hi)) ^ (rp & 15);
                    bf16x8 vf = *(const bf16x8*)(Vl + rp * 128 + ch * 8);
                    acc[dt] = __builtin_amdgcn_mfma_f32_32x32x16_bf16(pa.v, vf, acc[dt], 0, 0, 0);
                }
            }
            __builtin_amdgcn_s_setprio(0);
        }
    }

    const float dsum = d01[0] + d01[1] + d23[0] + d23[1];

    // merge sp halves through LDS (pure adds); write undivided partials
    __syncthreads();
    float* accb = (float*)pool;                    // [4 wq x 2 dt][16 r][64 l] = 32 KB
    float* ddb  = (float*)(pool + 32768);          // [8 wv][64 l] = 2 KB
    ddb[wv * 64 + l] = dsum;
    if (sp == 1) {
        #pragma unroll
        for (int dt = 0; dt < 2; ++dt)
            #pragma unroll
            for (int r = 0; r < 16; ++r)
                accb[(((wq * 2 + dt) * 16 + r) << 6) + l] = acc[dt][r];
    }
    __syncthreads();
    if (sp == 0) {
        short* po = (quart < 3) ? (short*)(poA + (size_t)quart * QSZ) : po3;
        float dq = ddb[(wq * 2) * 64 + q] + ddb[(wq * 2) * 64 + 32 + q]
                 + ddb[(wq * 2 + 1) * 64 + q] + ddb[(wq * 2 + 1) * 64 + 32 + q];
        if (hi == 0) pd[(size_t)quart * (NHEADS * S_LEN) + (size_t)h * S_LEN + q0 + wq * 32 + q] = dq;
        #pragma unroll
        for (int dt = 0; dt < 2; ++dt) {
            #pragma unroll
            for (int r = 0; r < 16; ++r) {
                float o = acc[dt][r] + accb[(((wq * 2 + dt) * 16 + r) << 6) + l];
                int qo = (r & 3) + 8 * (r >> 2) + 4 * hi;
                po[((size_t)h * S_LEN + q0 + wq * 32 + qo) * DKH + dt * 32 + q] = f2bf(o);
            }
        }
    }
}

extern "C" void kernel_launch(void* const* d_in, const int* in_sizes, int n_in,
                              void* d_out, int out_size, void* d_ws, size_t ws_size,
                              hipStream_t stream) {
    (void)in_sizes; (void)n_in; (void)out_size; (void)ws_size;
    const float* q  = (const float*)d_in[0];
    const float* k  = (const float*)d_in[1];
    const float* v  = (const float*)d_in[2];
    const float* Wq = (const float*)d_in[3];
    const float* bq = (const float*)d_in[4];
    const float* Wk = (const float*)d_in[5];
    const float* bk = (const float*)d_in[6];
    const float* Wv = (const float*)d_in[7];
    const float* bv = (const float*)d_in[8];
    const float* Wo = (const float*)d_in[9];
    const float* bo = (const float*)d_in[10];
    const int* mask = (const int*)d_in[11];

    char* ws = (char*)d_ws;
    short* qb  = (short*)(ws + 0);
    short* kb  = (short*)(ws + 6291456);
    short* vb  = (short*)(ws + 12582912);
    short* Wqb = (short*)(ws + 18874368);   // Wq/Wk/Wv/Wo contiguous, 1179648 B each
    short* Wkb = (short*)(ws + 20054016);
    short* Wvb = (short*)(ws + 21233664);
    short* Wob = (short*)(ws + 22413312);
    short* Qh  = (short*)(ws + 23592960);
    short* Kh  = (short*)(ws + 29884416);
    short* Vt  = (short*)(ws + 36175872);
    unsigned long long* mpT = (unsigned long long*)(ws + 42467328);
    // flash partials overlay DEAD regions (after qkv_gemm, W q/k/v + inputs are dead):
    short* poA = (short*)(ws + 0);          // quarters 0-2: 3 x 6291456 B = [0, 18874368)
    float* pd  = (float*)(ws + 18874368);   // 786432 B (over dead Wqb/Wkb space)
    short* po3 = (short*)(ws + 44564480);   // quarter 3: 6291456 B (old ctx region)
    // Wob at 22413312 stays live for gemm_out. Total ws use: 50855936 bytes.

    cvt_all<<<dim3(512, 1, 11), 256, 0, stream>>>(q, k, v, Wq, Wk, Wv, Wo, qb, kb, vb, Wqb, mask, mpT);

    qkv_gemm<<<dim3(S_LEN / 64, DMODEL / 128, 3), 256, 0, stream>>>(
        qb, kb, vb, Wqb, Wkb, Wvb, bq, bk, bv, Qh, Kh, Vt);

    flash_attn6<<<1536, 512, 0, stream>>>(Qh, Kh, Vt, mpT, poA, po3, pd);

    gemm_out<<<dim3(S_LEN / 64, DMODEL / 128), 256, 0, stream>>>(poA, po3, pd, Wob, bo, (float*)d_out);
}